// Round 2
// baseline (3523.752 us; speedup 1.0000x reference)
//
#include <hip/hip_runtime.h>
#include <hip/hip_bf16.h>
#include <cstddef>

#define H    50
#define G4   200   // 4*H
#define TT   1024
#define BB   512
#define BLK  512   // threads per block (8 waves)

__device__ __forceinline__ float sigm(float x) { return 1.0f / (1.0f + __expf(-x)); }
__device__ __forceinline__ float tanh_fast(float x) { return 1.0f - 2.0f / (__expf(2.0f * x) + 1.0f); }

// 25-wide dot, 4 accumulators; w is a register array (statically indexed after
// unroll), v points into LDS.
__device__ __forceinline__ float dot25(const float* __restrict__ w, const float* __restrict__ v) {
    float a0 = 0.f, a1 = 0.f, a2 = 0.f, a3 = 0.f;
#pragma unroll
    for (int k = 0; k < 24; k += 4) {
        a0 = __fmaf_rn(w[k + 0], v[k + 0], a0);
        a1 = __fmaf_rn(w[k + 1], v[k + 1], a1);
        a2 = __fmaf_rn(w[k + 2], v[k + 2], a2);
        a3 = __fmaf_rn(w[k + 3], v[k + 3], a3);
    }
    a0 = __fmaf_rn(w[24], v[24], a0);
    return (a0 + a2) + (a1 + a3);
}

// MODE 0: first layer (scalar x input, write h-seq)
// MODE 1: middle layer (vector input, write h-seq; in-place on ws is safe)
// MODE 2: last layer (vector input, no h-seq write, fused dense head)
//
// Decomposition: one block per batch element, 512 threads.
//   pair p = tid>>1 owns gate row p (p<200); half hf = tid&1 owns k-range
//   [hf*25, hf*25+25). 50 weight floats per thread -> register resident.
template <int MODE>
__global__ __launch_bounds__(BLK, 4) void lstm_kernel(
    const float* __restrict__ xin,     // MODE0: x [B][T]; else h_prev [B][T][H]
    const float* __restrict__ w_ih,    // [G4][H] (MODE0: [G4][1])
    const float* __restrict__ w_hh,    // [G4][H]
    const float* __restrict__ b_ih,    // [G4]
    const float* __restrict__ b_hh,    // [G4]
    float* __restrict__ hout,          // [B][T][H]  (MODE 0,1)
    const float* __restrict__ w_dense, // [H]    (MODE 2)
    const float* __restrict__ b_dense, // [1]    (MODE 2)
    float* __restrict__ out)           // [B]    (MODE 2)
{
    const int b   = blockIdx.x;
    const int tid = threadIdx.x;
    const int wv  = tid >> 6;   // wave 0..7
    const int ln  = tid & 63;   // lane
    const int p   = tid >> 1;   // gate row 0..255 (<200 active)
    const int hf  = tid & 1;    // k-half
    const int k0  = hf * 25;

    __shared__ float h_s[8][64];       // per-wave h copy (same-wave dep only)
    __shared__ float gates_s[2][G4];   // double-buffered gate pre-activations
    __shared__ float xin_s[2][64];     // MODE 1,2: double-buffered x_t
    __shared__ float x_s[TT];          // MODE 0: whole input row (4 KB)

    const bool active = (p < G4);

    // ---- per-thread weights in registers (50 floats) ----
    float whh_r[25];
    float wih_r[25];
    float wih0 = 0.f, bias_r = 0.f;
    if (active) {
        if (hf == 0) bias_r = b_ih[p] + b_hh[p];
#pragma unroll
        for (int k = 0; k < 25; k++) whh_r[k] = w_hh[p * H + k0 + k];
        if (MODE == 0) {
            if (hf == 0) wih0 = w_ih[p];
#pragma unroll
            for (int k = 0; k < 25; k++) wih_r[k] = 0.f;
        } else {
#pragma unroll
            for (int k = 0; k < 25; k++) wih_r[k] = w_ih[p * H + k0 + k];
        }
    } else {
#pragma unroll
        for (int k = 0; k < 25; k++) { whh_r[k] = 0.f; wih_r[k] = 0.f; }
    }
    float wd_r = 0.f;
    if (MODE == 2 && ln < H) wd_r = w_dense[ln];

    const float* __restrict__ xrow = xin + (size_t)b * TT * (MODE == 0 ? 1 : H);

    // ---- init LDS state + stage first inputs ----
    h_s[wv][ln] = 0.f;
    if (MODE == 0) {
        for (int i = tid; i < TT; i += BLK) x_s[i] = xrow[i];
    } else {
        if (tid < H) xin_s[0][tid] = xrow[tid];
    }
    float c_r = 0.f;     // cell state (lanes < H, replicated per wave)
    float hval = 0.f;
    __syncthreads();

    for (int t = 0; t < TT; t++) {
        const int pbuf = t & 1;
        // ---- async prefetch of x_{t+1}: issue loads EARLY (T14 split) ----
        float xpre = 0.f;
        const bool pre = (MODE != 0) && (tid >= 2 * G4) && (tid < 2 * G4 + H) && (t + 1 < TT);
        if (pre) xpre = xrow[(size_t)(t + 1) * H + (tid - 2 * G4)];

        // ---- phase 1: gate pre-activations (convergent across all lanes) ----
        float acc = dot25(whh_r, &h_s[wv][k0]);
        if (MODE == 0) {
            if (hf == 0) acc = __fmaf_rn(wih0, x_s[t], acc);
        } else {
            acc += dot25(wih_r, &xin_s[pbuf][k0]);
        }
        acc += __shfl_xor(acc, 1, 64);           // pair sum -> full 50-dot
        if (active && hf == 0) gates_s[pbuf][p] = acc + bias_r;

        // ---- land prefetch into the OTHER buffer (vmcnt drain here) ----
        if (pre) xin_s[pbuf ^ 1][tid - 2 * G4] = xpre;

        __syncthreads();   // the ONLY barrier per step

        // ---- phase 2: elementwise update, redundant in every wave ----
        if (ln < H) {
            float iv = sigm(gates_s[pbuf][ln]);
            float fv = sigm(gates_s[pbuf][H + ln]);
            float gv = tanh_fast(gates_s[pbuf][2 * H + ln]);
            float ov = sigm(gates_s[pbuf][3 * H + ln]);
            c_r = __fmaf_rn(fv, c_r, iv * gv);
            hval = ov * tanh_fast(c_r);
            h_s[wv][ln] = hval;
            if (MODE != 2 && wv == 0)
                hout[(size_t)b * TT * H + (size_t)t * H + ln] = hval;
        }
        // next phase-1 reads h_s[wv]: same-wave dependency -> no second barrier
    }

    // ---- dense head (MODE 2): out[b] = h_last . w_dense + b_dense ----
    if (MODE == 2 && wv == 0) {
        float v = (ln < H) ? hval * wd_r : 0.f;
#pragma unroll
        for (int off = 32; off > 0; off >>= 1) v += __shfl_down(v, off, 64);
        if (ln == 0) out[b] = v + b_dense[0];
    }
}

extern "C" void kernel_launch(void* const* d_in, const int* in_sizes, int n_in,
                              void* d_out, int out_size, void* d_ws, size_t ws_size,
                              hipStream_t stream) {
    const float* x     = (const float*)d_in[0];
    const float* wih1  = (const float*)d_in[1];
    const float* whh1  = (const float*)d_in[2];
    const float* bih1  = (const float*)d_in[3];
    const float* bhh1  = (const float*)d_in[4];
    const float* wih2  = (const float*)d_in[5];
    const float* whh2  = (const float*)d_in[6];
    const float* bih2  = (const float*)d_in[7];
    const float* bhh2  = (const float*)d_in[8];
    const float* wih3  = (const float*)d_in[9];
    const float* whh3  = (const float*)d_in[10];
    const float* bih3  = (const float*)d_in[11];
    const float* bhh3  = (const float*)d_in[12];
    const float* wd    = (const float*)d_in[13];
    const float* bd    = (const float*)d_in[14];
    float* outp = (float*)d_out;
    float* hbuf = (float*)d_ws;   // [B][T][H] fp32, used in-place by all layers

    lstm_kernel<0><<<BB, BLK, 0, stream>>>(x,    wih1, whh1, bih1, bhh1, hbuf, nullptr, nullptr, nullptr);
    lstm_kernel<1><<<BB, BLK, 0, stream>>>(hbuf, wih2, whh2, bih2, bhh2, hbuf, nullptr, nullptr, nullptr);
    lstm_kernel<2><<<BB, BLK, 0, stream>>>(hbuf, wih3, whh3, bih3, bhh3, nullptr, wd, bd, outp);
}

// Round 4
// 2711.314 us; speedup vs baseline: 1.2996x; 1.2996x over previous
//
#include <hip/hip_runtime.h>
#include <hip/hip_bf16.h>
#include <cstddef>

#define H    50
#define G4   200   // 4*H
#define TT   1024
#define BB   512
#define BLK  256   // threads per block: thread = gate row (200 active), 4 waves

__device__ __forceinline__ float sigm(float x) { return 1.0f / (1.0f + __expf(-x)); }
__device__ __forceinline__ float tanh_fast(float x) { return 1.0f - 2.0f / (__expf(2.0f * x) + 1.0f); }

__device__ __forceinline__ float4 f4mul(float4 a, float4 b) {
    return make_float4(a.x * b.x, a.y * b.y, a.z * b.z, a.w * b.w);
}
__device__ __forceinline__ float4 f4fma(float4 a, float4 b, float4 c) {
    return make_float4(__fmaf_rn(a.x, b.x, c.x), __fmaf_rn(a.y, b.y, c.y),
                       __fmaf_rn(a.z, b.z, c.z), __fmaf_rn(a.w, b.w, c.w));
}

// ---- weights as NAMED float4 registers: nothing for the compiler to demote ----
#define WDECL(P) float4 P##q0, P##q1, P##q2, P##q3, P##q4, P##q5, P##q6, P##q7, \
                        P##q8, P##q9, P##q10, P##q11; float P##s0, P##s1;

#define WLOAD(P, src) do { const float* _s = (src); \
    P##q0  = make_float4(_s[0],  _s[1],  _s[2],  _s[3]);  \
    P##q1  = make_float4(_s[4],  _s[5],  _s[6],  _s[7]);  \
    P##q2  = make_float4(_s[8],  _s[9],  _s[10], _s[11]); \
    P##q3  = make_float4(_s[12], _s[13], _s[14], _s[15]); \
    P##q4  = make_float4(_s[16], _s[17], _s[18], _s[19]); \
    P##q5  = make_float4(_s[20], _s[21], _s[22], _s[23]); \
    P##q6  = make_float4(_s[24], _s[25], _s[26], _s[27]); \
    P##q7  = make_float4(_s[28], _s[29], _s[30], _s[31]); \
    P##q8  = make_float4(_s[32], _s[33], _s[34], _s[35]); \
    P##q9  = make_float4(_s[36], _s[37], _s[38], _s[39]); \
    P##q10 = make_float4(_s[40], _s[41], _s[42], _s[43]); \
    P##q11 = make_float4(_s[44], _s[45], _s[46], _s[47]); \
    P##s0 = _s[48]; P##s1 = _s[49]; } while (0)

// vptr must be 16B-aligned LDS; 8 independent accumulation chains, depth 6.
#define WDOT(P, vptr, out) do { const float4* _v = (const float4*)(vptr); \
    float4 _a = f4mul(P##q0, _v[0]); \
    float4 _b = f4mul(P##q1, _v[1]); \
    _a = f4fma(P##q2,  _v[2],  _a); _b = f4fma(P##q3,  _v[3],  _b); \
    _a = f4fma(P##q4,  _v[4],  _a); _b = f4fma(P##q5,  _v[5],  _b); \
    _a = f4fma(P##q6,  _v[6],  _a); _b = f4fma(P##q7,  _v[7],  _b); \
    _a = f4fma(P##q8,  _v[8],  _a); _b = f4fma(P##q9,  _v[9],  _b); \
    _a = f4fma(P##q10, _v[10], _a); _b = f4fma(P##q11, _v[11], _b); \
    float _r = (_a.x + _b.x) + (_a.y + _b.y) + ((_a.z + _b.z) + (_a.w + _b.w)); \
    _r = __fmaf_rn(P##s0, (vptr)[48], _r); \
    _r = __fmaf_rn(P##s1, (vptr)[49], _r); \
    (out) += _r; } while (0)

// MODE 0: first layer (scalar x input, write h-seq)
// MODE 1: middle layer (vector input, write h-seq; in-place on ws is safe)
// MODE 2: last layer (vector input, no h-seq write, fused dense head)
template <int MODE>
__global__ __launch_bounds__(BLK, 2) void lstm_kernel(
    const float* __restrict__ xin,     // MODE0: x [B][T]; else h_prev [B][T][H]
    const float* __restrict__ w_ih,    // [G4][H] (MODE0: [G4][1])
    const float* __restrict__ w_hh,    // [G4][H]
    const float* __restrict__ b_ih,    // [G4]
    const float* __restrict__ b_hh,    // [G4]
    float* __restrict__ hout,          // [B][T][H]  (MODE 0,1)
    const float* __restrict__ w_dense, // [H]    (MODE 2)
    const float* __restrict__ b_dense, // [1]    (MODE 2)
    float* __restrict__ out)           // [B]    (MODE 2)
{
    const int b   = blockIdx.x;
    const int tid = threadIdx.x;
    const int wv  = tid >> 6;   // wave 0..3
    const int ln  = tid & 63;   // lane
    const int p   = tid;        // gate row (<200 active)
    const bool active = (p < G4);
    const int pr  = active ? p : (G4 - 1);   // clamp for safe loads; garbage unused

    __shared__ __align__(16) float h_s[4][64];     // per-wave h copy (same-wave dep only)
    __shared__ float gates_s[2][G4];               // double-buffered gate pre-activations
    __shared__ __align__(16) float xin_s[2][64];   // MODE 1,2: double-buffered x_t
    __shared__ float x_s[TT];                      // MODE 0: whole input row (4 KB)

    // ---- weights into named float4 registers ----
    WDECL(wh) WDECL(wx)
    float wx0 = 0.f;
    WLOAD(wh, w_hh + pr * H);
    if (MODE == 0) {
        wx0 = w_ih[pr];
    } else {
        WLOAD(wx, w_ih + pr * H);
    }
    const float bias = b_ih[pr] + b_hh[pr];
    float wd_r = 0.f;
    if (MODE == 2 && ln < H) wd_r = w_dense[ln];

    const float* __restrict__ xrow = xin + (size_t)b * TT * (MODE == 0 ? 1 : H);

    // ---- init LDS state + stage first inputs ----
    h_s[wv][ln] = 0.f;
    if (MODE == 0) {
        for (int i = tid; i < TT; i += BLK) x_s[i] = xrow[i];
    } else {
        if (tid < H) xin_s[0][tid] = xrow[tid];
    }
    float c_r = 0.f;     // cell state (lanes < H, replicated per wave)
    float hval = 0.f;
    __syncthreads();

    for (int t = 0; t < TT; t++) {
        const int pbuf = t & 1;
        // ---- async prefetch of x_{t+1}: issue load EARLY, land AFTER the dots ----
        float xpre = 0.f;
        const bool pre = (MODE != 0) && (tid >= G4) && (tid < G4 + H) && (t + 1 < TT);
        if (pre) xpre = xrow[(size_t)(t + 1) * H + (tid - G4)];

        // ---- phase 1: gate pre-activation (all lanes compute; LDS reads broadcast) ----
        float acc = bias;
        WDOT(wh, h_s[wv], acc);
        if (MODE == 0) {
            acc = __fmaf_rn(wx0, x_s[t], acc);
        } else {
            WDOT(wx, xin_s[pbuf], acc);
        }
        if (active) gates_s[pbuf][p] = acc;
        if (pre) xin_s[pbuf ^ 1][tid - G4] = xpre;

        __syncthreads();   // the ONLY barrier per step

        // ---- phase 2: elementwise update, redundant in every wave ----
        if (ln < H) {
            float iv = sigm(gates_s[pbuf][ln]);
            float fv = sigm(gates_s[pbuf][H + ln]);
            float gv = tanh_fast(gates_s[pbuf][2 * H + ln]);
            float ov = sigm(gates_s[pbuf][3 * H + ln]);
            c_r = __fmaf_rn(fv, c_r, iv * gv);
            hval = ov * tanh_fast(c_r);
            h_s[wv][ln] = hval;
            if (MODE != 2 && wv == 0)
                hout[(size_t)b * TT * H + (size_t)t * H + ln] = hval;
        }
        // next phase-1 reads h_s[wv]: same-wave dependency -> no second barrier
    }

    // ---- dense head (MODE 2): out[b] = h_last . w_dense + b_dense ----
    if (MODE == 2 && wv == 0) {
        float v = (ln < H) ? hval * wd_r : 0.f;
#pragma unroll
        for (int off = 32; off > 0; off >>= 1) v += __shfl_down(v, off, 64);
        if (ln == 0) out[b] = v + b_dense[0];
    }
}

extern "C" void kernel_launch(void* const* d_in, const int* in_sizes, int n_in,
                              void* d_out, int out_size, void* d_ws, size_t ws_size,
                              hipStream_t stream) {
    const float* x     = (const float*)d_in[0];
    const float* wih1  = (const float*)d_in[1];
    const float* whh1  = (const float*)d_in[2];
    const float* bih1  = (const float*)d_in[3];
    const float* bhh1  = (const float*)d_in[4];
    const float* wih2  = (const float*)d_in[5];
    const float* whh2  = (const float*)d_in[6];
    const float* bih2  = (const float*)d_in[7];
    const float* bhh2  = (const float*)d_in[8];
    const float* wih3  = (const float*)d_in[9];
    const float* whh3  = (const float*)d_in[10];
    const float* bih3  = (const float*)d_in[11];
    const float* bhh3  = (const float*)d_in[12];
    const float* wd    = (const float*)d_in[13];
    const float* bd    = (const float*)d_in[14];
    float* outp = (float*)d_out;
    float* hbuf = (float*)d_ws;   // [B][T][H] fp32, used in-place by all layers

    lstm_kernel<0><<<BB, BLK, 0, stream>>>(x,    wih1, whh1, bih1, bhh1, hbuf, nullptr, nullptr, nullptr);
    lstm_kernel<1><<<BB, BLK, 0, stream>>>(hbuf, wih2, whh2, bih2, bhh2, hbuf, nullptr, nullptr, nullptr);
    lstm_kernel<2><<<BB, BLK, 0, stream>>>(hbuf, wih3, whh3, bih3, bhh3, nullptr, wd, bd, outp);
}